// Round 3
// baseline (2233.780 us; speedup 1.0000x reference)
//
#include <hip/hip_runtime.h>
#include <math.h>

#define EMBED   2048
#define NEXP    64
#define BATCHN  16384
#define MTILE   32
#define KCH     64
#define NCHUNK  (EMBED / KCH)   // 32
#define WPAD    68              // W LDS row stride (floats): 16B-aligned, breaks bank conflicts
#define NTHREADS 128
#define MARGIN_THRESH 4e-4f     // fp32 logit error tail ~1e-5; 40x safety margin

__global__ __launch_bounds__(NTHREADS, 2)
void topk_gate_kernel(const float* __restrict__ x, const float* __restrict__ W,
                      const float* __restrict__ bias, float* __restrict__ out)
{
    // x tile: [32 rows][64 k] contiguous (global_load_lds requires contiguous lane order)
    __shared__ __align__(16) float xs[2][MTILE * KCH];    // 16 KB
    __shared__ __align__(16) float ws[2][NEXP * WPAD];    // 34.8 KB
    __shared__ unsigned int flagmask;                     // rows needing f64 recheck
    __shared__ double sh_dlog[NEXP];

    const int tid  = threadIdx.x;
    const int er   = tid & 15;            // expert group: experts er + 16j
    const int rr   = tid >> 4;            // row group 0..7: rows rr*4 + i
    const int wave = tid >> 6;            // 0..1
    const int lane = tid & 63;
    const int row0 = blockIdx.x * MTILE;

    const int lrow = lane >> 4;           // row within 4-row segment
    const int lk4  = (lane & 15) << 2;    // k offset in floats

    float acc[4][4] = {};
    float4 wreg[8];                       // W pipeline registers (global->VGPR->LDS)

    // ---- stage x chunk into xs[buf] via async global->LDS (width 16) ----
    auto stage_x = [&](int buf, int c) {
        const int kc = c * KCH;
        #pragma unroll
        for (int s4 = 0; s4 < 4; ++s4) {
            const int seg = wave * 4 + s4;                 // 0..7, 4 rows each
            const float* src = x + (size_t)(row0 + seg * 4 + lrow) * EMBED + kc + lk4;
            float* dst = (float*)&xs[buf][seg * 256];      // wave-uniform base; HW adds lane*16
            __builtin_amdgcn_global_load_lds(
                (const __attribute__((address_space(1))) void*)src,
                (__attribute__((address_space(3))) void*)dst,
                16, 0, 0);
        }
    };

    // ---- W chunk: coalesced global->VGPR ----
    auto load_w = [&](int c) {
        const int kc = c * KCH;
        #pragma unroll
        for (int r = 0; r < 8; ++r) {
            const int f = r * NTHREADS + tid;
            const int e = f >> 4, k4 = (f & 15) << 2;
            wreg[r] = *(const float4*)(W + (size_t)e * EMBED + kc + k4);
        }
    };
    auto store_w = [&](int buf) {
        #pragma unroll
        for (int r = 0; r < 8; ++r) {
            const int f = r * NTHREADS + tid;
            const int e = f >> 4, k4 = (f & 15) << 2;
            *(float4*)&ws[buf][e * WPAD + k4] = wreg[r];
        }
    };

    auto compute = [&](int buf) {
        #pragma unroll
        for (int kk = 0; kk < KCH / 4; ++kk) {
            float4 xv[4], wv[4];
            #pragma unroll
            for (int i = 0; i < 4; ++i)
                xv[i] = *(const float4*)&xs[buf][(rr * 4 + i) * KCH + kk * 4];
            #pragma unroll
            for (int j = 0; j < 4; ++j)
                wv[j] = *(const float4*)&ws[buf][(er + 16 * j) * WPAD + kk * 4];
            #pragma unroll
            for (int i = 0; i < 4; ++i)
                #pragma unroll
                for (int j = 0; j < 4; ++j)
                    acc[i][j] += xv[i].x * wv[j].x + xv[i].y * wv[j].y
                               + xv[i].z * wv[j].z + xv[i].w * wv[j].w;
        }
    };

    // ---- K loop, double-buffered ----
    stage_x(0, 0); load_w(0); store_w(0);
    if (tid == 0) flagmask = 0u;
    __syncthreads();
    #pragma unroll 1
    for (int c = 0; c < NCHUNK; c += 2) {
        stage_x(1, c + 1); load_w(c + 1);
        compute(0);
        store_w(1);
        __syncthreads();
        if (c + 2 < NCHUNK) { stage_x(0, c + 2); load_w(c + 2); }
        compute(1);
        if (c + 2 < NCHUNK) store_w(0);
        __syncthreads();
    }

    // ---- epilogue: bias, per-row top-3 over 64 experts (top-2 + margin) ----
    float bl[4];
    #pragma unroll
    for (int j = 0; j < 4; ++j) bl[j] = bias[er + 16 * j];

    #pragma unroll
    for (int i = 0; i < 4; ++i) {
        float v1 = -INFINITY, v2 = -INFINITY, v3 = -INFINITY;
        int i1 = 0, i2 = 0;
        #pragma unroll
        for (int j = 0; j < 4; ++j) {
            const float v = acc[i][j] + bl[j];
            const int e = er + 16 * j;
            if (v > v1)      { v3 = v2; v2 = v1; i2 = i1; v1 = v; i1 = e; }
            else if (v > v2) { v3 = v2; v2 = v;  i2 = e; }
            else if (v > v3) { v3 = v; }
        }
        // butterfly merge of sorted triples across the 16-lane expert group
        #pragma unroll
        for (int m = 1; m <= 8; m <<= 1) {
            const float o1  = __shfl_xor(v1, m, 64);
            const int   oi1 = __shfl_xor(i1, m, 64);
            const float o2  = __shfl_xor(v2, m, 64);
            const int   oi2 = __shfl_xor(i2, m, 64);
            const float o3  = __shfl_xor(v3, m, 64);
            if (o1 > v1) {
                float nv2; int ni2; float nv3;
                if (v1 > o2) { nv2 = v1; ni2 = i1; nv3 = fmaxf(v2, o2); }
                else         { nv2 = o2; ni2 = oi2; nv3 = fmaxf(v1, o3); }
                v1 = o1; i1 = oi1; v2 = nv2; i2 = ni2; v3 = nv3;
            } else {
                if (o1 > v2) { v3 = fmaxf(v2, o2); v2 = o1; i2 = oi1; }
                else         { v3 = fmaxf(v3, o1); }
            }
        }
        if (er == 0) {
            const int row = row0 + rr * 4 + i;
            const float margin = fminf(v1 - v2, v2 - v3);
            if (margin < MARGIN_THRESH) {
                atomicOr(&flagmask, 1u << (rr * 4 + i));   // exact recheck below
            } else {
                const float e2  = __expf(v2 - v1);
                const float inv = 1.0f / (1.0f + e2);
                *(float2*)&out[row * 2]              = make_float2(inv, e2 * inv);
                *(float2*)&out[2 * BATCHN + row * 2] = make_float2((float)i1, (float)i2);
            }
        }
    }

    // ---- exact f64 recompute for near-tie rows (rare: ~1% of rows) ----
    __syncthreads();
    unsigned int mask = flagmask;          // uniform across block
    while (mask) {
        const int r = __builtin_ctz(mask);
        mask &= mask - 1;
        const int e = tid >> 1, h = tid & 1;   // 2 threads per expert, half-K each
        const float* xr = x + (size_t)(row0 + r) * EMBED + h * 1024;
        const float* wr = W + (size_t)e * EMBED + h * 1024;
        double s = 0.0;
        #pragma unroll 4
        for (int k = 0; k < 1024; k += 4) {
            const float4 xv = *(const float4*)(xr + k);
            const float4 wv = *(const float4*)(wr + k);
            s += (double)xv.x * (double)wv.x;
            s += (double)xv.y * (double)wv.y;
            s += (double)xv.z * (double)wv.z;
            s += (double)xv.w * (double)wv.w;
        }
        s += __shfl_xor(s, 1, 64);             // partner lane: same expert, other half
        if (h == 0) sh_dlog[e] = s + (double)bias[e];
        __syncthreads();
        if (tid == 0) {
            double v1 = -1e300, v2 = -1e300; int i1 = 0, i2 = 0;
            for (int ee = 0; ee < NEXP; ++ee) {     // ascending: ties keep lower index
                const double v = sh_dlog[ee];
                if (v > v1)      { v2 = v1; i2 = i1; v1 = v; i1 = ee; }
                else if (v > v2) { v2 = v; i2 = ee; }
            }
            const int row = row0 + r;
            const double ex  = exp(v2 - v1);
            const double inv = 1.0 / (1.0 + ex);
            out[row * 2]                  = (float)inv;
            out[row * 2 + 1]              = (float)(ex * inv);
            out[2 * BATCHN + row * 2]     = (float)i1;
            out[2 * BATCHN + row * 2 + 1] = (float)i2;
        }
        __syncthreads();
    }
}

extern "C" void kernel_launch(void* const* d_in, const int* in_sizes, int n_in,
                              void* d_out, int out_size, void* d_ws, size_t ws_size,
                              hipStream_t stream) {
    const float* x = (const float*)d_in[0];
    const float* W = (const float*)d_in[1];
    const float* b = (const float*)d_in[2];
    float* out = (float*)d_out;
    dim3 grid(BATCHN / MTILE);   // 512 blocks
    dim3 block(NTHREADS);        // 128 threads
    topk_gate_kernel<<<grid, block, 0, stream>>>(x, W, b, out);
}